// Round 4
// baseline (1263.156 us; speedup 1.0000x reference)
//
#include <hip/hip_runtime.h>

#define NN 100000
#define NE 1280000
#define D  64

#define BINSZ   512                       // nodes per bin
#define NBIN    ((NN + BINSZ - 1) / BINSZ)   // 196
#define ESTRIDE 7168                      // slots per bin (avg 6554, +7.6 sigma)
#define CHUNK   4096                      // edges per bin_scatter block

typedef unsigned int   uint;
typedef unsigned short ushort;
typedef unsigned char  uchar;
typedef __attribute__((ext_vector_type(8))) short short8v;   // 8 bf16 (4 VGPR)
typedef __attribute__((ext_vector_type(4))) float f32x4;

// float -> bf16 round-to-nearest-even
__device__ __forceinline__ ushort f2bf(float f) {
    uint u = __float_as_uint(f);
    uint r = (u + 0x7fffu + ((u >> 16) & 1u)) >> 16;
    return (ushort)r;
}
__device__ __forceinline__ float bf2f(ushort h) {
    return __uint_as_float(((uint)h) << 16);
}
__device__ __forceinline__ float bfhi_f(uint w) { return __uint_as_float(w & 0xffff0000u); }
__device__ __forceinline__ float bflo_f(uint w) { return __uint_as_float(w << 16); }

// ---------------------------------------------------------------------------
// prep: x (fp32) -> xb (bf16 pairs packed in uint)
// ---------------------------------------------------------------------------
__global__ __launch_bounds__(256) void prep_x(const float* __restrict__ x,
                                              uint* __restrict__ xb) {
    int i = blockIdx.x * 256 + threadIdx.x;      // uint index; total NN*32
    if (i < NN * 32) {
        float2 v = ((const float2*)x)[i];
        xb[i] = (uint)f2bf(v.x) | ((uint)f2bf(v.y) << 16);
    }
}

// prep: 4 weight matrices fp32 -> hi/lo bf16 (error compensation split)
__global__ __launch_bounds__(256) void prep_w(const float* __restrict__ w0,
                                              const float* __restrict__ w1,
                                              const float* __restrict__ w2,
                                              const float* __restrict__ w3,
                                              ushort* __restrict__ hi,
                                              ushort* __restrict__ lo) {
    int g = blockIdx.x * 256 + threadIdx.x;      // 4*4096
    if (g < 4 * 4096) {
        int m = g >> 12;
        const float* src = (m == 0) ? w0 : (m == 1) ? w1 : (m == 2) ? w2 : w3;
        float f = src[g & 4095];
        ushort h = f2bf(f);
        hi[g] = h;
        lo[g] = f2bf(f - bf2f(h));
    }
}

// ---------------------------------------------------------------------------
// bin_scatter: group edges by 512-node dst-bin with DENSE writes.
// Block stages CHUNK edges: LDS histogram -> block scan -> LDS placement ->
// one global atomicAdd per (block, nonempty bin) claims contiguous space ->
// coalesced run copy-out. Packed edge: (src << 9) | (dst & 511), 26 bits.
// ---------------------------------------------------------------------------
__global__ __launch_bounds__(256) void bin_scatter(const int* __restrict__ srcv,
                                                   const int* __restrict__ dstv,
                                                   int* __restrict__ bincur,
                                                   uint* __restrict__ ecol) {
    __shared__ uint  ebuf[CHUNK];     // 16 KB, edges grouped by bin
    __shared__ uchar bbuf[CHUNK];     // 4 KB, bin of each staged edge
    __shared__ int hist[256];
    __shared__ int hbase[256];
    __shared__ int cur[256];
    __shared__ int gbase[256];

    const int tid  = threadIdx.x;
    const int base = blockIdx.x * CHUNK;

    hist[tid] = 0;
    __syncthreads();

    uint pk[16];
    int  bn[16];
    #pragma unroll
    for (int r = 0; r < 16; ++r) {
        const int e = base + r * 256 + tid;
        if (e < NE) {
            const int d = dstv[e];
            bn[r] = d >> 9;
            pk[r] = ((uint)srcv[e] << 9) | (uint)(d & 511);
            atomicAdd(&hist[bn[r]], 1);
        } else {
            bn[r] = -1;
        }
    }
    __syncthreads();

    // inclusive Hillis-Steele scan of hist into hbase, then make exclusive
    int v = hist[tid];
    hbase[tid] = v;
    __syncthreads();
    for (int d = 1; d < 256; d <<= 1) {
        int t = (tid >= d) ? hbase[tid - d] : 0;
        __syncthreads();
        hbase[tid] += t;
        __syncthreads();
    }
    const int excl = hbase[tid] - v;    // own-index read, safe
    hbase[tid] = excl;
    cur[tid]   = excl;
    __syncthreads();

    // LDS placement (order within bin is arbitrary -- fine for a sum)
    #pragma unroll
    for (int r = 0; r < 16; ++r) {
        if (bn[r] >= 0) {
            const int p = atomicAdd(&cur[bn[r]], 1);
            ebuf[p] = pk[r];
            bbuf[p] = (uchar)bn[r];
        }
    }
    // claim contiguous global space per nonempty bin
    if (tid < NBIN && hist[tid] > 0)
        gbase[tid] = atomicAdd(&bincur[tid], hist[tid]);
    __syncthreads();

    const int n = min(CHUNK, NE - base);
    for (int i = tid; i < n; i += 256) {
        const int b   = bbuf[i];
        const int pib = gbase[b] + (i - hbase[b]);
        if (pib < ESTRIDE)                       // defensive (cannot overflow)
            ecol[(size_t)b * ESTRIDE + pib] = ebuf[i];
    }
}

// ---------------------------------------------------------------------------
// bin_aggregate: one block per bin; 512x64 fp32 accumulators in LDS
// (lo/hi bf16-halves planes, conflict-free ds_add_f32). Half-wave per edge,
// 8 row-gathers in flight per wave. Degrees counted in LDS. Emits packed
// bf16 mean rows.
// ---------------------------------------------------------------------------
__global__ __launch_bounds__(1024) void bin_aggregate(const uint* __restrict__ xb,
                                                      const uint* __restrict__ ecol,
                                                      const int* __restrict__ bincur,
                                                      uint* __restrict__ meanb) {
    __shared__ float lop[BINSZ * 32];   // 64 KB: feature 2i   (lo half)
    __shared__ float hip_[BINSZ * 32];  // 64 KB: feature 2i+1 (hi half)
    __shared__ int   cntp[BINSZ];       // 2 KB degrees

    const int bin  = blockIdx.x;
    const int tid  = threadIdx.x;
    const int lane = tid & 63;
    const int wv   = tid >> 6;          // 0..15
    const int i32  = lane & 31;
    const int half = lane >> 5;

    for (int i = tid; i < BINSZ * 32; i += 1024) { lop[i] = 0.f; hip_[i] = 0.f; }
    for (int i = tid; i < BINSZ; i += 1024) cntp[i] = 0;
    __syncthreads();

    const int s = bin * ESTRIDE;
    const int n = min(bincur[bin], ESTRIDE);

    // contiguous per-wave split of the bin's edge list
    const int per = (n + 15) >> 4;
    const int ws_ = min(wv * per, n);
    const int we_ = min(ws_ + per, n);

    for (int j = ws_; j < we_; j += 16) {
        const int rem = we_ - j;                 // >= 1
        // degree counts: lanes 0..15 handle one edge each
        if (lane < 16 && lane < rem) {
            uint pc = ecol[s + j + lane];
            atomicAdd(&cntp[pc & 511], 1);
        }
        uint w[8]; int dl[8]; bool ok[8];
        #pragma unroll
        for (int u = 0; u < 8; ++u) {
            const int eidx = 2 * u + half;       // 0..15
            ok[u] = (eidx < rem);
            // may read <=16 slots into next bin's region (padded); clamp src
            const uint p = ecol[s + j + eidx];
            dl[u] = (int)(p & 511);
            const int srcn = min((int)(p >> 9), NN - 1);
            w[u] = xb[(size_t)srcn * 32 + i32];  // 8 gathers in flight
        }
        #pragma unroll
        for (int u = 0; u < 8; ++u) {
            if (ok[u]) {
                atomicAdd(&lop[dl[u] * 32 + i32],  bflo_f(w[u]));
                atomicAdd(&hip_[dl[u] * 32 + i32], bfhi_f(w[u]));
            }
        }
    }
    __syncthreads();

    // mean + pack bf16 pairs, dense coalesced write
    const int nodebase = bin * BINSZ;
    for (int t = tid; t < BINSZ * 32; t += 1024) {
        const int nl   = t >> 5;
        const int node = nodebase + nl;
        if (node < NN) {
            const float inv = 1.0f / (float)max(cntp[nl], 1);
            const int ii = t & 31;
            const float f0 = lop[nl * 32 + ii] * inv;
            const float f1 = hip_[nl * 32 + ii] * inv;
            meanb[(size_t)node * 32 + ii] = (uint)f2bf(f0) | ((uint)f2bf(f1) << 16);
        }
    }
}

// ---------------------------------------------------------------------------
// combine GEMM: out[m][n] = mean[m]@Wl^T + self[m]@Wr^T + b (+relu)
// wave per 16-node M-tile; mfma_f32_16x16x32_bf16. (unchanged from round 3)
// ---------------------------------------------------------------------------
template<int SELF_BF16, int WF32, int WB16>
__global__ __launch_bounds__(256) void gemm_combine(
        const ushort* __restrict__ meanb,
        const float*  __restrict__ selff,
        const ushort* __restrict__ selfb,
        const ushort* __restrict__ wl_hi, const ushort* __restrict__ wl_lo,
        const ushort* __restrict__ wr_hi, const ushort* __restrict__ wr_lo,
        const float*  __restrict__ bias,
        float* __restrict__ outf, ushort* __restrict__ outb,
        int do_relu)
{
    const int l    = threadIdx.x & 63;
    const int wid  = (blockIdx.x * 256 + threadIdx.x) >> 6;
    const int nw   = gridDim.x * 4;
    const int m16  = l & 15;
    const int koff = (l >> 4) * 8;
    const int NT   = NN / 16;      // 6250

    for (int tile = wid; tile < NT; tile += nw) {
        const int mbase = tile * 16;

        short8v am[2], ashi[2], aslo[2];
        #pragma unroll
        for (int kk = 0; kk < 2; ++kk) {
            const size_t ro = (size_t)(mbase + m16) * 64 + kk * 32 + koff;
            am[kk] = *(const short8v*)(meanb + ro);
            if (SELF_BF16) {
                ashi[kk] = *(const short8v*)(selfb + ro);
            } else {
                const float4* xp = (const float4*)(selff + ro);
                float4 v0 = xp[0], v1 = xp[1];
                float vv[8] = {v0.x, v0.y, v0.z, v0.w, v1.x, v1.y, v1.z, v1.w};
                short8v h, lo2;
                #pragma unroll
                for (int j = 0; j < 8; ++j) {
                    ushort hb_ = f2bf(vv[j]);
                    h[j]   = (short)hb_;
                    lo2[j] = (short)f2bf(vv[j] - bf2f(hb_));
                }
                ashi[kk] = h;
                aslo[kk] = lo2;
            }
        }

        #pragma unroll
        for (int nt = 0; nt < 4; ++nt) {
            f32x4 acc = {0.f, 0.f, 0.f, 0.f};
            #pragma unroll
            for (int kk = 0; kk < 2; ++kk) {
                const size_t wo = (size_t)(nt * 16 + m16) * 64 + kk * 32 + koff;
                short8v bwlh = *(const short8v*)(wl_hi + wo);
                short8v bwll = *(const short8v*)(wl_lo + wo);
                short8v bwrh = *(const short8v*)(wr_hi + wo);
                short8v bwrl = *(const short8v*)(wr_lo + wo);
                acc = __builtin_amdgcn_mfma_f32_16x16x32_bf16(am[kk],  bwlh, acc, 0, 0, 0);
                acc = __builtin_amdgcn_mfma_f32_16x16x32_bf16(am[kk],  bwll, acc, 0, 0, 0);
                acc = __builtin_amdgcn_mfma_f32_16x16x32_bf16(ashi[kk], bwrh, acc, 0, 0, 0);
                if (!SELF_BF16)
                    acc = __builtin_amdgcn_mfma_f32_16x16x32_bf16(aslo[kk], bwrh, acc, 0, 0, 0);
                acc = __builtin_amdgcn_mfma_f32_16x16x32_bf16(ashi[kk], bwrl, acc, 0, 0, 0);
            }
            const float bv = bias[nt * 16 + m16];
            #pragma unroll
            for (int r = 0; r < 4; ++r) {
                float v = acc[r] + bv;
                if (do_relu) v = fmaxf(v, 0.f);
                const size_t oi = (size_t)(mbase + (l >> 4) * 4 + r) * 64 + nt * 16 + m16;
                if (WF32) outf[oi] = v;
                if (WB16) outb[oi] = f2bf(v);
            }
        }
    }
}

// ---------------------------------------------------------------------------
extern "C" void kernel_launch(void* const* d_in, const int* in_sizes, int n_in,
                              void* d_out, int out_size, void* d_ws, size_t ws_size,
                              hipStream_t stream) {
    const float* x   = (const float*)d_in[0];
    const int*   ei  = (const int*)d_in[1];     // [2, NE] int32
    const float* W1l = (const float*)d_in[2];
    const float* b1  = (const float*)d_in[3];
    const float* W1r = (const float*)d_in[4];
    const float* W2l = (const float*)d_in[5];
    const float* b2  = (const float*)d_in[6];
    const float* W2r = (const float*)d_in[7];
    float*       out = (float*)d_out;

    const int* src = ei;
    const int* dst = ei + NE;

    // ---- workspace layout (base usage ~31.3 MB, proven available) ----
    char* p = (char*)d_ws;
    int*    bincur = (int*)p;    p += 1024;                              // 256 ints
    uint*   ecol   = (uint*)p;   p += (size_t)NBIN * ESTRIDE * 4 + 64;   // 5.62 MB (+pad)
    ushort* whi    = (ushort*)p; p += (size_t)4 * 4096 * 2;              // 32 KB
    ushort* wlo    = (ushort*)p; p += (size_t)4 * 4096 * 2;              // 32 KB
    uint*   xb     = (uint*)p;   p += (size_t)NN * 32 * 4;               // 12.8 MB (reused as hb)
    uint*   meanb  = (uint*)p;   p += (size_t)NN * 32 * 4;               // 12.8 MB
    float*  hf     = (float*)p;                                          // +25.6 MB (big only)
    const bool big = ws_size >= (size_t)(p - (char*)d_ws) + (size_t)NN * D * 4;

    // weight order in whi/wlo: 0=W1l, 1=W1r, 2=W2l, 3=W2r
    const ushort* w1l_hi = whi;             const ushort* w1l_lo = wlo;
    const ushort* w1r_hi = whi + 4096;      const ushort* w1r_lo = wlo + 4096;
    const ushort* w2l_hi = whi + 2 * 4096;  const ushort* w2l_lo = wlo + 2 * 4096;
    const ushort* w2r_hi = whi + 3 * 4096;  const ushort* w2r_lo = wlo + 3 * 4096;

    hipMemsetAsync(bincur, 0, 1024, stream);

    // ---- prep ----
    prep_x<<<(NN * 32 + 255) / 256, 256, 0, stream>>>(x, xb);
    prep_w<<<(4 * 4096 + 255) / 256, 256, 0, stream>>>(W1l, W1r, W2l, W2r, whi, wlo);

    // ---- bin edges (shared by both layers) ----
    bin_scatter<<<(NE + CHUNK - 1) / CHUNK, 256, 0, stream>>>(src, dst, bincur, ecol);

    // ---- layer 1 ----
    bin_aggregate<<<NBIN, 1024, 0, stream>>>(xb, ecol, bincur, meanb);
    if (big) {
        gemm_combine<0, 1, 1><<<1024, 256, 0, stream>>>(
            (const ushort*)meanb, x, nullptr,
            w1l_hi, w1l_lo, w1r_hi, w1r_lo, b1, hf, (ushort*)xb, 1);
    } else {
        gemm_combine<0, 0, 1><<<1024, 256, 0, stream>>>(
            (const ushort*)meanb, x, nullptr,
            w1l_hi, w1l_lo, w1r_hi, w1r_lo, b1, nullptr, (ushort*)xb, 1);
    }

    // ---- layer 2 (h bf16 lives in xb region) ----
    bin_aggregate<<<NBIN, 1024, 0, stream>>>(xb, ecol, bincur, meanb);
    if (big) {
        gemm_combine<0, 1, 0><<<1024, 256, 0, stream>>>(
            (const ushort*)meanb, hf, nullptr,
            w2l_hi, w2l_lo, w2r_hi, w2r_lo, b2, out, nullptr, 0);
    } else {
        gemm_combine<1, 1, 0><<<1024, 256, 0, stream>>>(
            (const ushort*)meanb, nullptr, (const ushort*)xb,
            w2l_hi, w2l_lo, w2r_hi, w2r_lo, b2, out, nullptr, 0);
    }
}

// Round 5
// 249.821 us; speedup vs baseline: 5.0562x; 5.0562x over previous
//
#include <hip/hip_runtime.h>

#define NN 100000
#define NE 1280000
#define D  64

#define BINSZ   512
#define NBIN    196            // ceil(NN/512); 196*512 = 100352
#define ESTRIDE 7168           // max edges/bin (mean 6554, +7.6 sigma)
#define CHUNK   4096           // edges per bin_scatter block
#define NT      (NN / 16)      // 6250 MFMA node-tiles (NN % 16 == 0)

typedef unsigned int   uint;
typedef unsigned short ushort;
typedef unsigned char  uchar;
typedef __attribute__((ext_vector_type(8))) short short8v;   // 8 bf16
typedef __attribute__((ext_vector_type(4))) float f32x4;

// float -> bf16 round-to-nearest-even
__device__ __forceinline__ ushort f2bf(float f) {
    uint u = __float_as_uint(f);
    uint r = (u + 0x7fffu + ((u >> 16) & 1u)) >> 16;
    return (ushort)r;
}
__device__ __forceinline__ float bf2f(ushort h) {
    return __uint_as_float(((uint)h) << 16);
}
__device__ __forceinline__ float bfhi_f(uint w) { return __uint_as_float(w & 0xffff0000u); }
__device__ __forceinline__ float bflo_f(uint w) { return __uint_as_float(w << 16); }

// ---------------------------------------------------------------------------
// prep: x (fp32) -> xb (bf16 pairs packed in uint); layout == ushort[NN][64]
// ---------------------------------------------------------------------------
__global__ __launch_bounds__(256) void prep_x(const float* __restrict__ x,
                                              uint* __restrict__ xb) {
    int i = blockIdx.x * 256 + threadIdx.x;
    if (i < NN * 32) {
        float2 v = ((const float2*)x)[i];
        xb[i] = (uint)f2bf(v.x) | ((uint)f2bf(v.y) << 16);
    }
}

// prep: 4 weight matrices fp32 -> hi/lo bf16 split
__global__ __launch_bounds__(256) void prep_w(const float* __restrict__ w0,
                                              const float* __restrict__ w1,
                                              const float* __restrict__ w2,
                                              const float* __restrict__ w3,
                                              ushort* __restrict__ hi,
                                              ushort* __restrict__ lo) {
    int g = blockIdx.x * 256 + threadIdx.x;
    if (g < 4 * 4096) {
        int m = g >> 12;
        const float* src = (m == 0) ? w0 : (m == 1) ? w1 : (m == 2) ? w2 : w3;
        float f = src[g & 4095];
        ushort h = f2bf(f);
        hi[g] = h;
        lo[g] = f2bf(f - bf2f(h));
    }
}

// ---------------------------------------------------------------------------
// bin_scatter: group edges by 512-node dst-bin with dense run writes.
// Packed edge: (src << 9) | (dst & 511).
// ---------------------------------------------------------------------------
__global__ __launch_bounds__(256) void bin_scatter(const int* __restrict__ srcv,
                                                   const int* __restrict__ dstv,
                                                   int* __restrict__ bincur,
                                                   uint* __restrict__ ecol) {
    __shared__ uint  ebuf[CHUNK];
    __shared__ uchar bbuf[CHUNK];
    __shared__ int hist[256];
    __shared__ int hbase[256];
    __shared__ int cur[256];
    __shared__ int gbase[256];

    const int tid  = threadIdx.x;
    const int base = blockIdx.x * CHUNK;

    hist[tid] = 0;
    __syncthreads();

    uint pk[16];
    int  bn[16];
    #pragma unroll
    for (int r = 0; r < 16; ++r) {
        const int e = base + r * 256 + tid;
        if (e < NE) {
            const int d = dstv[e];
            bn[r] = d >> 9;
            pk[r] = ((uint)srcv[e] << 9) | (uint)(d & 511);
            atomicAdd(&hist[bn[r]], 1);
        } else {
            bn[r] = -1;
        }
    }
    __syncthreads();

    int v = hist[tid];
    hbase[tid] = v;
    __syncthreads();
    for (int d = 1; d < 256; d <<= 1) {
        int t = (tid >= d) ? hbase[tid - d] : 0;
        __syncthreads();
        hbase[tid] += t;
        __syncthreads();
    }
    const int excl = hbase[tid] - v;
    hbase[tid] = excl;
    cur[tid]   = excl;
    __syncthreads();

    #pragma unroll
    for (int r = 0; r < 16; ++r) {
        if (bn[r] >= 0) {
            const int p = atomicAdd(&cur[bn[r]], 1);
            ebuf[p] = pk[r];
            bbuf[p] = (uchar)bn[r];
        }
    }
    if (tid < NBIN && hist[tid] > 0)
        gbase[tid] = atomicAdd(&bincur[tid], hist[tid]);
    __syncthreads();

    const int n = min(CHUNK, NE - base);
    for (int i = tid; i < n; i += 256) {
        const int b   = bbuf[i];
        const int pib = gbase[b] + (i - hbase[b]);
        if (pib < ESTRIDE)
            ecol[(size_t)b * ESTRIDE + pib] = ebuf[i];
    }
}

// ---------------------------------------------------------------------------
// binscan: exclusive scan of per-bin counts -> binbase; also offs[NN] = total
// ---------------------------------------------------------------------------
__global__ __launch_bounds__(256) void binscan(const int* __restrict__ bincur,
                                               int* __restrict__ binbase,
                                               int* __restrict__ offs) {
    __shared__ int buf[256];
    const int t = threadIdx.x;
    int v = (t < NBIN) ? min(bincur[t], ESTRIDE) : 0;
    buf[t] = v;
    __syncthreads();
    for (int d = 1; d < 256; d <<= 1) {
        int tv = (t >= d) ? buf[t - d] : 0;
        __syncthreads();
        buf[t] += tv;
        __syncthreads();
    }
    if (t < NBIN) binbase[t] = buf[t] - v;
    if (t == 0) {
        binbase[NBIN] = buf[255];
        offs[NN]      = buf[255];
    }
}

// ---------------------------------------------------------------------------
// binsort: one block per bin; LDS counting-sort by node -> node-sorted col
// (dense coalesced writes) + per-node CSR offsets.
// ---------------------------------------------------------------------------
__global__ __launch_bounds__(1024) void binsort(const uint* __restrict__ ecol,
                                                const int* __restrict__ bincur,
                                                const int* __restrict__ binbase,
                                                int* __restrict__ col,
                                                int* __restrict__ offs) {
    __shared__ int hist[512];
    __shared__ int cnt_[512];
    __shared__ int cur[512];
    __shared__ int colbuf[ESTRIDE];

    const int b = blockIdx.x;
    const int t = threadIdx.x;
    const int n    = min(bincur[b], ESTRIDE);
    const int gsrc = b * ESTRIDE;
    const int gdst = binbase[b];

    if (t < 512) hist[t] = 0;
    __syncthreads();

    for (int i = t; i < n; i += 1024)
        atomicAdd(&hist[ecol[gsrc + i] & 511], 1);
    __syncthreads();

    if (t < 512) cnt_[t] = hist[t];
    __syncthreads();
    for (int d = 1; d < 512; d <<= 1) {
        int tv = (t >= d && t < 512) ? hist[t - d] : 0;
        __syncthreads();
        if (t < 512) hist[t] += tv;
        __syncthreads();
    }
    if (t < 512) {
        const int excl = hist[t] - cnt_[t];
        cur[t] = excl;
        const int node = b * BINSZ + t;
        if (node < NN) offs[node] = gdst + excl;
    }
    __syncthreads();

    for (int i = t; i < n; i += 1024) {
        const uint e = ecol[gsrc + i];
        const int  p = atomicAdd(&cur[e & 511], 1);
        colbuf[p] = (int)(e >> 9);
    }
    __syncthreads();

    for (int i = t; i < n; i += 1024)
        col[gdst + i] = colbuf[i];
}

// ---------------------------------------------------------------------------
// fused_layer: wave per 16-node tile. Lane l accumulates features
// [8q, 8q+8) (q = l>>4) of node (l&15) directly in MFMA A-frag layout:
// neighbor row loads from packed-bf16 xb, lanes {l, l+16, l+32, l+48} cover a
// full 64B half-row; 8 loads in flight; no LDS, no barriers. Then the
// round-3-verified MFMA combine (W hi/lo split) + bias/relu epilogue.
// ---------------------------------------------------------------------------
template<int SELF_BF16, int WF32, int WB16>
__global__ __launch_bounds__(256) void fused_layer(
        const uint*   __restrict__ gsrc,   // packed bf16 gather source [NN][32]
        const float*  __restrict__ selff,  // fp32 self rows (layer 1)
        const ushort* __restrict__ selfb,  // bf16 self rows (layer 2)
        const int*    __restrict__ col,
        const int*    __restrict__ offs,
        const ushort* __restrict__ wl_hi, const ushort* __restrict__ wl_lo,
        const ushort* __restrict__ wr_hi, const ushort* __restrict__ wr_lo,
        const float*  __restrict__ bias,
        float* __restrict__ outf, ushort* __restrict__ outb,
        int do_relu)
{
    const int l   = threadIdx.x & 63;
    const int wid = (blockIdx.x * 256 + threadIdx.x) >> 6;
    if (wid >= NT) return;
    const int m16  = l & 15;
    const int q    = l >> 4;         // 0..3
    const int koff = q * 8;
    const int mbase = wid * 16;
    const int node  = mbase + m16;

    const int o0  = offs[node];
    const int deg = offs[node + 1] - o0;

    // ---- aggregate neighbors straight into A-frag layout ----
    float acc[16];
    #pragma unroll
    for (int j = 0; j < 16; ++j) acc[j] = 0.f;

    for (int k0 = 0;; k0 += 4) {
        if (!__any(k0 < deg)) break;
        int id[4];
        #pragma unroll
        for (int u = 0; u < 4; ++u) {
            const int k = k0 + u;
            id[u] = (k < deg) ? col[o0 + k] : -1;
        }
        uint4 r0[4], r1[4];
        #pragma unroll
        for (int u = 0; u < 4; ++u) {
            if (id[u] >= 0) {
                const uint* row = gsrc + (size_t)id[u] * 32;
                r0[u] = *(const uint4*)(row + 4 * q);        // feats koff..koff+7
                r1[u] = *(const uint4*)(row + 16 + 4 * q);   // feats 32+koff..
            }
        }
        #pragma unroll
        for (int u = 0; u < 4; ++u) {
            if (id[u] >= 0) {
                uint w;
                w = r0[u].x; acc[0]  += bflo_f(w); acc[1]  += bfhi_f(w);
                w = r0[u].y; acc[2]  += bflo_f(w); acc[3]  += bfhi_f(w);
                w = r0[u].z; acc[4]  += bflo_f(w); acc[5]  += bfhi_f(w);
                w = r0[u].w; acc[6]  += bflo_f(w); acc[7]  += bfhi_f(w);
                w = r1[u].x; acc[8]  += bflo_f(w); acc[9]  += bfhi_f(w);
                w = r1[u].y; acc[10] += bflo_f(w); acc[11] += bfhi_f(w);
                w = r1[u].z; acc[12] += bflo_f(w); acc[13] += bfhi_f(w);
                w = r1[u].w; acc[14] += bflo_f(w); acc[15] += bfhi_f(w);
            }
        }
    }

    const float inv = 1.0f / (float)max(deg, 1);
    short8v am[2];
    #pragma unroll
    for (int j = 0; j < 8; ++j) {
        am[0][j] = (short)f2bf(acc[j] * inv);
        am[1][j] = (short)f2bf(acc[8 + j] * inv);
    }

    // ---- self fragments ----
    short8v ashi[2], aslo[2];
    if (SELF_BF16) {
        ashi[0] = *(const short8v*)(selfb + (size_t)node * 64 + koff);
        ashi[1] = *(const short8v*)(selfb + (size_t)node * 64 + 32 + koff);
    } else {
        #pragma unroll
        for (int kk = 0; kk < 2; ++kk) {
            const float4* xp = (const float4*)(selff + (size_t)node * 64 + kk * 32 + koff);
            float4 v0 = xp[0], v1 = xp[1];
            float vv[8] = {v0.x, v0.y, v0.z, v0.w, v1.x, v1.y, v1.z, v1.w};
            #pragma unroll
            for (int j = 0; j < 8; ++j) {
                ushort hb_ = f2bf(vv[j]);
                ashi[kk][j] = (short)hb_;
                aslo[kk][j] = (short)f2bf(vv[j] - bf2f(hb_));
            }
        }
    }

    // ---- MFMA combine (round-3-verified mapping) ----
    #pragma unroll
    for (int nt = 0; nt < 4; ++nt) {
        f32x4 acc4 = {0.f, 0.f, 0.f, 0.f};
        #pragma unroll
        for (int kk = 0; kk < 2; ++kk) {
            const size_t wo = (size_t)(nt * 16 + m16) * 64 + kk * 32 + koff;
            short8v bwlh = *(const short8v*)(wl_hi + wo);
            short8v bwll = *(const short8v*)(wl_lo + wo);
            short8v bwrh = *(const short8v*)(wr_hi + wo);
            short8v bwrl = *(const short8v*)(wr_lo + wo);
            acc4 = __builtin_amdgcn_mfma_f32_16x16x32_bf16(am[kk],   bwlh, acc4, 0, 0, 0);
            acc4 = __builtin_amdgcn_mfma_f32_16x16x32_bf16(am[kk],   bwll, acc4, 0, 0, 0);
            acc4 = __builtin_amdgcn_mfma_f32_16x16x32_bf16(ashi[kk], bwrh, acc4, 0, 0, 0);
            if (!SELF_BF16)
                acc4 = __builtin_amdgcn_mfma_f32_16x16x32_bf16(aslo[kk], bwrh, acc4, 0, 0, 0);
            acc4 = __builtin_amdgcn_mfma_f32_16x16x32_bf16(ashi[kk], bwrl, acc4, 0, 0, 0);
        }
        const float bv = bias[nt * 16 + m16];
        #pragma unroll
        for (int r = 0; r < 4; ++r) {
            float v = acc4[r] + bv;
            if (do_relu) v = fmaxf(v, 0.f);
            const size_t oi = (size_t)(mbase + q * 4 + r) * 64 + nt * 16 + m16;
            if (WF32) outf[oi] = v;
            if (WB16) outb[oi] = f2bf(v);
        }
    }
}

// ---------------------------------------------------------------------------
extern "C" void kernel_launch(void* const* d_in, const int* in_sizes, int n_in,
                              void* d_out, int out_size, void* d_ws, size_t ws_size,
                              hipStream_t stream) {
    const float* x   = (const float*)d_in[0];
    const int*   ei  = (const int*)d_in[1];     // [2, NE] int32
    const float* W1l = (const float*)d_in[2];
    const float* b1  = (const float*)d_in[3];
    const float* W1r = (const float*)d_in[4];
    const float* W2l = (const float*)d_in[5];
    const float* b2  = (const float*)d_in[6];
    const float* W2r = (const float*)d_in[7];
    float*       out = (float*)d_out;

    const int* src = ei;
    const int* dst = ei + NE;

    // ---- workspace layout (~31.2 MB; ecol aliased inside hb) ----
    char* p = (char*)d_ws;
    int*    bincur  = (int*)p;    p += 1024;
    int*    binbase = (int*)p;    p += 1024;
    int*    col     = (int*)p;    p += (size_t)NE * 4;        // 5.12 MB
    int*    offs    = (int*)p;    p += (size_t)(NN + 1) * 4 + 60;  // 0.4 MB
    ushort* whi     = (ushort*)p; p += (size_t)4 * 4096 * 2;  // 32 KB
    ushort* wlo     = (ushort*)p; p += (size_t)4 * 4096 * 2;  // 32 KB
    uint*   xb      = (uint*)p;   p += (size_t)NN * 32 * 4;   // 12.8 MB
    uint*   hb      = (uint*)p;   p += (size_t)NN * 32 * 4;   // 12.8 MB
    uint*   ecol    = hb;   // 5.62 MB, dead before hb is written (stream-serial)

    const ushort* w1l_hi = whi;             const ushort* w1l_lo = wlo;
    const ushort* w1r_hi = whi + 4096;      const ushort* w1r_lo = wlo + 4096;
    const ushort* w2l_hi = whi + 2 * 4096;  const ushort* w2l_lo = wlo + 2 * 4096;
    const ushort* w2r_hi = whi + 3 * 4096;  const ushort* w2r_lo = wlo + 3 * 4096;

    hipMemsetAsync(bincur, 0, 1024, stream);

    // ---- prep ----
    prep_x<<<(NN * 32 + 255) / 256, 256, 0, stream>>>(x, xb);
    prep_w<<<(4 * 4096 + 255) / 256, 256, 0, stream>>>(W1l, W1r, W2l, W2r, whi, wlo);

    // ---- CSR build (bin-grouped, all writes dense) ----
    bin_scatter<<<(NE + CHUNK - 1) / CHUNK, 256, 0, stream>>>(src, dst, bincur, ecol);
    binscan<<<1, 256, 0, stream>>>(bincur, binbase, offs);
    binsort<<<NBIN, 1024, 0, stream>>>(ecol, bincur, binbase, col, offs);

    // ---- layer 1: gather xb, self x (fp32), write h (bf16) ----
    fused_layer<0, 0, 1><<<(NT * 64 + 255) / 256, 256, 0, stream>>>(
        xb, x, nullptr, col, offs,
        w1l_hi, w1l_lo, w1r_hi, w1r_lo, b1, nullptr, (ushort*)hb, 1);

    // ---- layer 2: gather hb, self hb (bf16), write out (fp32) ----
    fused_layer<1, 1, 0><<<(NT * 64 + 255) / 256, 256, 0, stream>>>(
        hb, nullptr, (const ushort*)hb, col, offs,
        w2l_hi, w2l_lo, w2r_hi, w2r_lo, b2, out, nullptr, 0);
}